// Round 2
// baseline (4338.650 us; speedup 1.0000x reference)
//
#include <hip/hip_runtime.h>

#define B_   32
#define P_   24
#define H_   24
#define E_   300
#define D_   512
#define TWOD 1024
#define G4   4096

typedef __attribute__((ext_vector_type(8))) short bf16x8;
typedef __attribute__((ext_vector_type(4))) float f32x4;

__device__ __forceinline__ float bf2f(unsigned int u) {
    return __uint_as_float(u << 16);
}
__device__ __forceinline__ unsigned short f2bf(float f) {
    unsigned int x = __float_as_uint(f);
    unsigned int r = (x + 0x7fffu + ((x >> 16) & 1u)) >> 16;
    return (unsigned short)r;
}
__device__ __forceinline__ float sigf(float x) {
    return 1.0f / (1.0f + __expf(-x));
}
__device__ __forceinline__ float tanh_f(float x) {
    return 2.0f / (1.0f + __expf(-2.0f * x)) - 1.0f;
}

// ---------------------------------------------------------------------------
// generic f32 -> bf16 converter, 8 elems/thread (n divisible by 2048*... we
// launch with exact grids; guard anyway)
// ---------------------------------------------------------------------------
__global__ void k_cvt(const float* __restrict__ src, unsigned short* __restrict__ dst, int n) {
    int i = (blockIdx.x * 256 + threadIdx.x) * 8;
    if (i + 8 <= n) {
        float4 a = *(const float4*)(src + i);
        float4 b = *(const float4*)(src + i + 4);
        unsigned short o[8] = {f2bf(a.x), f2bf(a.y), f2bf(a.z), f2bf(a.w),
                               f2bf(b.x), f2bf(b.y), f2bf(b.z), f2bf(b.w)};
        *(uint4*)(dst + i) = *(const uint4*)o;
    }
}

// ---------------------------------------------------------------------------
// K0a: gather embeddings (f32) -> bf16, zero-pad K 300->320
// grid: 768 blocks (i*32+b), block: 320 threads
// ---------------------------------------------------------------------------
__global__ void k_embed(const int* __restrict__ prem, const int* __restrict__ hyp,
                        const float* __restrict__ emb,
                        unsigned short* __restrict__ PX, unsigned short* __restrict__ HX) {
    int rb = blockIdx.x;          // i*32 + b
    int i = rb >> 5, b = rb & 31;
    int t = threadIdx.x;          // 0..319
    int tp = prem[b * P_ + i];
    int th = hyp[b * H_ + i];
    float vp = (t < E_) ? emb[(size_t)tp * E_ + t] : 0.0f;
    float vh = (t < E_) ? emb[(size_t)th * E_ + t] : 0.0f;
    PX[rb * 320 + t] = f2bf(vp);
    HX[rb * 320 + t] = f2bf(vh);
}

// ---------------------------------------------------------------------------
// K0b: Apre[i,b,n] = px_i . W_ih[:, :300].T + b_ih + b_hh   (z=0)
//      Cpre[j,b,n] = hx_j . W_ih[:, 300:].T                  (z=1)
// M=768, N=4096, K=320 (padded). grid (6,32,2), block 256. Output bf16.
// ---------------------------------------------------------------------------
__global__ __launch_bounds__(256) void k_pre(
        const unsigned short* __restrict__ PX, const unsigned short* __restrict__ HX,
        const float* __restrict__ Wih,
        const float* __restrict__ bih, const float* __restrict__ bhh,
        unsigned short* __restrict__ Apre, unsigned short* __restrict__ Cpre) {
    int mt = blockIdx.x, nt = blockIdx.y, z = blockIdx.z;
    const unsigned short* X = z ? HX : PX;
    int koff = z ? E_ : 0;
    unsigned short* Out = z ? Cpre : Apre;

    __shared__ __align__(16) unsigned short At[128][72];
    __shared__ __align__(16) unsigned short Bt[128][72];

    int t = threadIdx.x;
    int lane = t & 63, wv = t >> 6;
    int wm = wv >> 1, wn = wv & 1;
    int l16 = lane & 15, quad = lane >> 4;

    f32x4 acc[4][4] = {};

    for (int s = 0; s < 5; ++s) {
        int k0 = s * 64;
        {   // stage A: 128 x 64 bf16 (already zero-padded past 300)
            int rr = t >> 1, p = (t & 1) * 32;
            const uint4* src = (const uint4*)(X + (size_t)(mt * 128 + rr) * 320 + k0 + p);
            uint4* dst = (uint4*)&At[rr][p];
            dst[0] = src[0]; dst[1] = src[1]; dst[2] = src[2]; dst[3] = src[3];
        }
        {   // stage B: Bt[r][c] = bf16(Wih[n0+r][koff + k0 + c]), zero past 300
            int r = t >> 1, p = (t & 1) * 32;
            int n = nt * 128 + r;
            const float* wrow = Wih + (size_t)n * (2 * E_) + koff;
            unsigned short* dst = &Bt[r][p];
            for (int c4 = 0; c4 < 8; ++c4) {
                int k = k0 + p + c4 * 4;
                if (k < E_) {
                    float4 v = *(const float4*)(wrow + k);
                    dst[c4 * 4 + 0] = f2bf(v.x); dst[c4 * 4 + 1] = f2bf(v.y);
                    dst[c4 * 4 + 2] = f2bf(v.z); dst[c4 * 4 + 3] = f2bf(v.w);
                } else {
                    dst[c4 * 4 + 0] = 0; dst[c4 * 4 + 1] = 0;
                    dst[c4 * 4 + 2] = 0; dst[c4 * 4 + 3] = 0;
                }
            }
        }
        __syncthreads();
        for (int ks = 0; ks < 2; ++ks) {
            bf16x8 a[4], bb[4];
            for (int mi = 0; mi < 4; ++mi)
                a[mi] = *(const bf16x8*)&At[wm * 64 + mi * 16 + l16][ks * 32 + quad * 8];
            for (int ni = 0; ni < 4; ++ni)
                bb[ni] = *(const bf16x8*)&Bt[wn * 64 + ni * 16 + l16][ks * 32 + quad * 8];
            for (int mi = 0; mi < 4; ++mi)
                for (int ni = 0; ni < 4; ++ni)
                    acc[mi][ni] = __builtin_amdgcn_mfma_f32_16x16x32_bf16(
                        a[mi], bb[ni], acc[mi][ni], 0, 0, 0);
        }
        __syncthreads();
    }

    for (int mi = 0; mi < 4; ++mi) {
        int rbase = mt * 128 + wm * 64 + mi * 16 + quad * 4;
        for (int ni = 0; ni < 4; ++ni) {
            int n = nt * 128 + wn * 64 + ni * 16 + l16;
            float bias = (z == 0) ? (bih[n] + bhh[n]) : 0.0f;
            for (int r = 0; r < 4; ++r)
                Out[(size_t)(rbase + r) * G4 + n] = f2bf(acc[mi][ni][r] + bias);
        }
    }
}

// ---------------------------------------------------------------------------
// K1: per-diagonal gate GEMM + fused LSTM activation.
// M = ncells*32 (<=768), K=1024 (hcat = [left_h | lower_h]), N-tile = 32 units
// x 4 gate strips (128 cols). grid (6,32), block 256.
// Whh is pre-converted bf16. Writes H2/C2 [cell][b][1024] (f32).
// ---------------------------------------------------------------------------
__global__ __launch_bounds__(256) void k_gates(
        int d,
        const float* __restrict__ Hbuf, const float* __restrict__ Cbuf,
        const unsigned short* __restrict__ Apre, const unsigned short* __restrict__ Cpre,
        const unsigned short* __restrict__ Whh,
        float* __restrict__ H2, float* __restrict__ C2) {
    int j_lo = (d > P_ - 1) ? d - (P_ - 1) : 0;
    int j_hi = (d < H_ - 1) ? d : H_ - 1;
    int Mrows = (j_hi - j_lo + 1) * 32;
    int mt = blockIdx.x, nt = blockIdx.y;
    if (mt * 128 >= Mrows) return;

    const float* Hp = Hbuf + (size_t)((d + 1) & 1) * (H_ * 32 * D_);
    const float* Cp = Cbuf + (size_t)((d + 1) & 1) * (H_ * 32 * D_);

    __shared__ __align__(16) unsigned char smem[36864];
    unsigned short (*At)[72] = (unsigned short (*)[72])smem;
    unsigned short (*Bt)[72] = (unsigned short (*)[72])(smem + 18432);

    int t = threadIdx.x;
    int lane = t & 63, wv = t >> 6;
    int wm = wv >> 1, wn = wv & 1;
    int l16 = lane & 15, quad = lane >> 4;

    f32x4 acc[4][4] = {};

    for (int s = 0; s < 16; ++s) {
        int k0 = s * 64;
        {   // stage A: hcat rows, f32 -> bf16, boundary zeros
            int rr = t >> 1, p = (t & 1) * 32;
            int rm = mt * 128 + rr;
            int kk = k0 + p;
            const float* src = nullptr;
            if (rm < Mrows) {
                int c = rm >> 5, b = rm & 31;
                int j = j_lo + c, i = d - j;
                if (kk < D_) { if (i > 0) src = Hp + (size_t)(j * 32 + b) * D_ + kk; }
                else         { if (j > 0) src = Hp + (size_t)((j - 1) * 32 + b) * D_ + (kk - D_); }
            }
            unsigned short* dst = &At[rr][p];
            if (src) {
                for (int q4 = 0; q4 < 8; ++q4) {
                    float4 v = ((const float4*)src)[q4];
                    dst[q4 * 4 + 0] = f2bf(v.x); dst[q4 * 4 + 1] = f2bf(v.y);
                    dst[q4 * 4 + 2] = f2bf(v.z); dst[q4 * 4 + 3] = f2bf(v.w);
                }
            } else {
                for (int c4 = 0; c4 < 32; ++c4) dst[c4] = 0;
            }
        }
        {   // stage B: 4 gate strips of 32 W_hh rows (bf16, direct copy)
            int r = t >> 1, p = (t & 1) * 32;
            int q = r >> 5, u = r & 31;
            const unsigned short* wrow =
                Whh + (size_t)(q * TWOD + nt * 32 + u) * TWOD + k0 + p;
            const uint4* s4 = (const uint4*)wrow;
            uint4* dst = (uint4*)&Bt[r][p];
            dst[0] = s4[0]; dst[1] = s4[1]; dst[2] = s4[2]; dst[3] = s4[3];
        }
        __syncthreads();
        for (int ks = 0; ks < 2; ++ks) {
            bf16x8 a[4], bb[4];
            for (int mi = 0; mi < 4; ++mi)
                a[mi] = *(const bf16x8*)&At[wm * 64 + mi * 16 + l16][ks * 32 + quad * 8];
            for (int ni = 0; ni < 4; ++ni)
                bb[ni] = *(const bf16x8*)&Bt[wn * 64 + ni * 16 + l16][ks * 32 + quad * 8];
            for (int mi = 0; mi < 4; ++mi)
                for (int ni = 0; ni < 4; ++ni)
                    acc[mi][ni] = __builtin_amdgcn_mfma_f32_16x16x32_bf16(
                        a[mi], bb[ni], acc[mi][ni], 0, 0, 0);
        }
        __syncthreads();
    }

    // Epilogue in two halves so the f32 D-tile fits the aliased 36 KB LDS.
    float* Dt = (float*)smem;   // [64][132]
    int u = t & 31;
    for (int half = 0; half < 2; ++half) {
        __syncthreads();
        if (wm == half) {
            for (int mi = 0; mi < 4; ++mi) {
                int rl = mi * 16 + quad * 4;
                for (int ni = 0; ni < 4; ++ni) {
                    int ccol = wn * 64 + ni * 16 + l16;
                    for (int r = 0; r < 4; ++r)
                        Dt[(rl + r) * 132 + ccol] = acc[mi][ni][r];
                }
            }
        }
        __syncthreads();
        for (int pass = 0; pass < 8; ++pass) {
            int rl = (t >> 5) + pass * 8;          // 0..63
            int rm = mt * 128 + half * 64 + rl;
            if (rm < Mrows) {
                int c = rm >> 5, b = rm & 31;
                int j = j_lo + c, i = d - j;
                int k = nt * 32 + u;               // unit in [0,1024)
                size_t ai = (size_t)(i * 32 + b) * G4 + k;
                size_t ci = (size_t)(j * 32 + b) * G4 + k;
                float g0 = Dt[rl * 132 +      u] + bf2f(Apre[ai])        + bf2f(Cpre[ci]);
                float g1 = Dt[rl * 132 + 32 + u] + bf2f(Apre[ai + 1024]) + bf2f(Cpre[ci + 1024]);
                float g2 = Dt[rl * 132 + 64 + u] + bf2f(Apre[ai + 2048]) + bf2f(Cpre[ci + 2048]);
                float g3 = Dt[rl * 132 + 96 + u] + bf2f(Apre[ai + 3072]) + bf2f(Cpre[ci + 3072]);
                float ccat;
                if (k < D_) ccat = (i > 0) ? Cp[(size_t)(j * 32 + b) * D_ + k] : 0.0f;
                else        ccat = (j > 0) ? Cp[(size_t)((j - 1) * 32 + b) * D_ + (k - D_)] : 0.0f;
                float si = sigf(g0), sf = sigf(g1), tg = tanh_f(g2), so = sigf(g3);
                float c2v = sf * ccat + si * tg;
                float h2v = so * tanh_f(c2v);
                H2[(size_t)(c * 32 + b) * TWOD + k] = h2v;
                C2[(size_t)(c * 32 + b) * TWOD + k] = c2v;
            }
        }
    }
}

// ---------------------------------------------------------------------------
// K2: condense. z=0: Hbuf[d&1] = H2 . W_ch.T + b_ch ; z=1: Cbuf = C2 . W_cc.T + b_cc
// M<=768, K=1024, N=512. grid (6,4,2), block 256. W pre-converted bf16.
// ---------------------------------------------------------------------------
__global__ __launch_bounds__(256) void k_cond(
        int d, const float* __restrict__ H2, const float* __restrict__ C2,
        const unsigned short* __restrict__ Wch, const unsigned short* __restrict__ Wcc,
        const float* __restrict__ bch, const float* __restrict__ bcc,
        float* __restrict__ Hbuf, float* __restrict__ Cbuf) {
    int j_lo = (d > P_ - 1) ? d - (P_ - 1) : 0;
    int j_hi = (d < H_ - 1) ? d : H_ - 1;
    int Mrows = (j_hi - j_lo + 1) * 32;
    int mt = blockIdx.x, nt = blockIdx.y, z = blockIdx.z;
    if (mt * 128 >= Mrows) return;

    const float* Ain = z ? C2 : H2;
    const unsigned short* W = z ? Wcc : Wch;
    const float* bias = z ? bcc : bch;
    float* Out = (z ? Cbuf : Hbuf) + (size_t)(d & 1) * (H_ * 32 * D_);

    __shared__ __align__(16) unsigned short At[128][72];
    __shared__ __align__(16) unsigned short Bt[128][72];

    int t = threadIdx.x;
    int lane = t & 63, wv = t >> 6;
    int wm = wv >> 1, wn = wv & 1;
    int l16 = lane & 15, quad = lane >> 4;

    f32x4 acc[4][4] = {};

    for (int s = 0; s < 16; ++s) {
        int k0 = s * 64;
        {   // stage A: f32 -> bf16
            int rr = t >> 1, p = (t & 1) * 32;
            int rm = mt * 128 + rr;
            unsigned short* dst = &At[rr][p];
            if (rm < Mrows) {
                const float* src = Ain + (size_t)rm * TWOD + k0 + p;
                for (int q4 = 0; q4 < 8; ++q4) {
                    float4 v = ((const float4*)src)[q4];
                    dst[q4 * 4 + 0] = f2bf(v.x); dst[q4 * 4 + 1] = f2bf(v.y);
                    dst[q4 * 4 + 2] = f2bf(v.z); dst[q4 * 4 + 3] = f2bf(v.w);
                }
            } else {
                for (int c4 = 0; c4 < 32; ++c4) dst[c4] = 0;
            }
        }
        {   // stage B (bf16 direct)
            int r = t >> 1, p = (t & 1) * 32;
            const uint4* s4 = (const uint4*)(W + (size_t)(nt * 128 + r) * TWOD + k0 + p);
            uint4* dst = (uint4*)&Bt[r][p];
            dst[0] = s4[0]; dst[1] = s4[1]; dst[2] = s4[2]; dst[3] = s4[3];
        }
        __syncthreads();
        for (int ks = 0; ks < 2; ++ks) {
            bf16x8 a[4], bb[4];
            for (int mi = 0; mi < 4; ++mi)
                a[mi] = *(const bf16x8*)&At[wm * 64 + mi * 16 + l16][ks * 32 + quad * 8];
            for (int ni = 0; ni < 4; ++ni)
                bb[ni] = *(const bf16x8*)&Bt[wn * 64 + ni * 16 + l16][ks * 32 + quad * 8];
            for (int mi = 0; mi < 4; ++mi)
                for (int ni = 0; ni < 4; ++ni)
                    acc[mi][ni] = __builtin_amdgcn_mfma_f32_16x16x32_bf16(
                        a[mi], bb[ni], acc[mi][ni], 0, 0, 0);
        }
        __syncthreads();
    }

    for (int mi = 0; mi < 4; ++mi) {
        int rbase = mt * 128 + wm * 64 + mi * 16 + quad * 4;
        for (int ni = 0; ni < 4; ++ni) {
            int n = nt * 128 + wn * 64 + ni * 16 + l16;
            float bs = bias[n];
            for (int r = 0; r < 4; ++r) {
                int rm = rbase + r;
                if (rm < Mrows) {
                    int c = rm >> 5, b = rm & 31;
                    int j = j_lo + c;
                    Out[(size_t)(j * 32 + b) * D_ + n] = acc[mi][ni][r] + bs;
                }
            }
        }
    }
}

// ---------------------------------------------------------------------------
// MLP layers (full f32)
// ---------------------------------------------------------------------------
__global__ void k_mlp1(const float* __restrict__ hin, const float* __restrict__ W,
                       const float* __restrict__ bias, float* __restrict__ outv) {
    int g = blockIdx.x * 256 + threadIdx.x;   // 0..16383
    int col = g & 511, b = g >> 9;
    const float* h = hin + (size_t)b * D_;
    const float* w = W + (size_t)col * D_;
    float acc = bias[col];
    for (int k = 0; k < D_; k += 4) {
        float4 wv = *(const float4*)(w + k);
        float4 hv = *(const float4*)(h + k);
        acc += hv.x * wv.x + hv.y * wv.y + hv.z * wv.z + hv.w * wv.w;
    }
    outv[(size_t)b * D_ + col] = fmaxf(acc, 0.0f);
}

__global__ void k_mlp3(const float* __restrict__ t2, const float* __restrict__ W3,
                       const float* __restrict__ b3, float* __restrict__ out) {
    __shared__ float lg[32][3];
    int t = threadIdx.x;
    if (t < 96) {
        int b = t / 3, cls = t % 3;
        const float* h = t2 + (size_t)b * D_;
        const float* w = W3 + (size_t)cls * D_;
        float acc = b3[cls];
        for (int k = 0; k < D_; k += 4) {
            float4 wv = *(const float4*)(w + k);
            float4 hv = *(const float4*)(h + k);
            acc += hv.x * wv.x + hv.y * wv.y + hv.z * wv.z + hv.w * wv.w;
        }
        lg[b][cls] = acc;
    }
    __syncthreads();
    if (t < 32) {
        float a = lg[t][0], bb = lg[t][1], c = lg[t][2];
        float m = fmaxf(a, fmaxf(bb, c));
        float ea = __expf(a - m), eb = __expf(bb - m), ec = __expf(c - m);
        float s = 1.0f / (ea + eb + ec);
        out[t * 3 + 0] = ea * s;
        out[t * 3 + 1] = eb * s;
        out[t * 3 + 2] = ec * s;
    }
}

// ---------------------------------------------------------------------------
extern "C" void kernel_launch(void* const* d_in, const int* in_sizes, int n_in,
                              void* d_out, int out_size, void* d_ws, size_t ws_size,
                              hipStream_t stream) {
    (void)in_sizes; (void)n_in; (void)out_size; (void)ws_size;

    const int* prem = (const int*)d_in[0];
    const int* hyp  = (const int*)d_in[1];
    const float* emb = (const float*)d_in[2];
    const float* Wih = (const float*)d_in[3];
    const float* Whh = (const float*)d_in[4];
    const float* bih = (const float*)d_in[5];
    const float* bhh = (const float*)d_in[6];
    const float* Wch = (const float*)d_in[7];
    const float* bch = (const float*)d_in[8];
    const float* Wcc = (const float*)d_in[9];
    const float* bcc = (const float*)d_in[10];
    const float* W1  = (const float*)d_in[11];
    const float* b1  = (const float*)d_in[12];
    const float* W2  = (const float*)d_in[13];
    const float* b2  = (const float*)d_in[14];
    const float* W3  = (const float*)d_in[15];
    const float* b3  = (const float*)d_in[16];
    float* out = (float*)d_out;

    // workspace layout (bytes, all 16B-aligned)
    char* wsb = (char*)d_ws;
    float* Hb  = (float*)(wsb + 0);                       // 2*24*32*512 f32
    float* Cb  = (float*)(wsb + 3145728);                 // 2*24*32*512 f32
    float* H2  = (float*)(wsb + 6291456);                 // 24*32*1024 f32
    float* C2  = (float*)(wsb + 9437184);                 // 24*32*1024 f32
    float* T1  = (float*)(wsb + 12582912);                // 32*512 f32
    float* T2v = (float*)(wsb + 12648448);                // 32*512 f32
    unsigned short* Apre  = (unsigned short*)(wsb + 12713984);  // 768*4096 bf16
    unsigned short* Cpre  = (unsigned short*)(wsb + 19005440);  // 768*4096 bf16
    unsigned short* WhhB  = (unsigned short*)(wsb + 25296896);  // 4096*1024 bf16
    unsigned short* WchB  = (unsigned short*)(wsb + 33685504);  // 512*1024 bf16
    unsigned short* WccB  = (unsigned short*)(wsb + 34734080);  // 512*1024 bf16
    unsigned short* PX    = (unsigned short*)(wsb + 35782656);  // 768*320 bf16
    unsigned short* HX    = (unsigned short*)(wsb + 36274176);  // 768*320 bf16

    k_cvt<<<2048, 256, 0, stream>>>(Whh, WhhB, G4 * TWOD);
    k_cvt<<<256, 256, 0, stream>>>(Wch, WchB, D_ * TWOD);
    k_cvt<<<256, 256, 0, stream>>>(Wcc, WccB, D_ * TWOD);
    k_embed<<<768, 320, 0, stream>>>(prem, hyp, emb, PX, HX);
    k_pre<<<dim3(6, 32, 2), 256, 0, stream>>>(PX, HX, Wih, bih, bhh, Apre, Cpre);

    for (int d = 0; d < P_ + H_ - 1; ++d) {
        k_gates<<<dim3(6, 32), 256, 0, stream>>>(d, Hb, Cb, Apre, Cpre, WhhB, H2, C2);
        k_cond<<<dim3(6, 4, 2), 256, 0, stream>>>(d, H2, C2, WchB, WccB, bch, bcc, Hb, Cb);
    }

    const float* hfin = Hb + (size_t)(H_ - 1) * 32 * D_;   // parity 0, j=23
    k_mlp1<<<64, 256, 0, stream>>>(hfin, W1, b1, T1);
    k_mlp1<<<64, 256, 0, stream>>>(T1, W2, b2, T2v);
    k_mlp3<<<1, 128, 0, stream>>>(T2v, W3, b3, out);
}